// Round 2
// baseline (617.911 us; speedup 1.0000x reference)
//
#include <hip/hip_runtime.h>
#include <stdint.h>

typedef unsigned int u32;
typedef unsigned long long u64;

constexpr int L   = 4;
constexpr int S   = 4;
constexpr int NM  = 16;   // n_max
constexpr int HID = 32;   // hidden
constexpr int BLK = 256;
constexpr int WPL = 3072; // floats of weights per l per species: 512+1024+1024+512

// ws header (ints): [0..3] counts, [4..7] cursors, [8..12] basePad,
//                   [13] fp32 flag, [14] int64 flag; perm at int offset 16

__global__ void k0_init(int* hdr) {
    if (threadIdx.x < 16) hdr[threadIdx.x] = 0;
}

// Runtime dtype detection (deterministic for fixed inputs; graph-capture safe).
__global__ void k_detect(const u32* __restrict__ rfw, const u32* __restrict__ spw,
                         int* __restrict__ hdr) {
    int t = threadIdx.x;  // 64 threads, one wave
    // fp32 vs bf16: low u16 of a word is a real bf16 value (plausible exponent)
    // iff the buffer is packed bf16; for fp32 it is uniform mantissa bits.
    u32 w  = rfw[t];
    u32 lo = w & 0xffffu;
    u32 e  = (lo >> 7) & 0xffu;
    int plausible = (lo == 0u || (e >= 90u && e <= 141u)) ? 1 : 0;
    u64 pm = __ballot(plausible);
    // int64 species => every odd u32 word is zero (values < 4, little-endian)
    u64 om = __ballot(spw[2 * t + 1] != 0u);
    if (t == 0) {
        hdr[13] = (__popcll(pm) < 48) ? 1 : 0;  // 1 => floats are fp32
        hdr[14] = (om == 0ull) ? 1 : 0;         // 1 => species is int64
    }
}

__device__ __forceinline__ int load_species(const int* sp, int i64, int n) {
    return i64 ? sp[2 * n] : sp[n];  // low word holds the value (< 4)
}

__global__ void k1_hist(const int* __restrict__ sp, int* __restrict__ hdr, int N) {
    __shared__ int cnt[S];
    int t = threadIdx.x;
    int n = blockIdx.x * BLK + t;
    if (t < S) cnt[t] = 0;
    int i64 = hdr[14];
    __syncthreads();
    if (n < N) atomicAdd(&cnt[load_species(sp, i64, n)], 1);
    __syncthreads();
    if (t < S) atomicAdd(&hdr[t], cnt[t]);
}

__global__ void k2_scan(int* __restrict__ hdr, int* __restrict__ perm) {
    __shared__ int bp[S + 1];
    __shared__ int cs[S];
    int t = threadIdx.x;
    if (t == 0) {
        int acc = 0;
        for (int s = 0; s < S; s++) {
            bp[s] = acc;
            cs[s] = hdr[s];
            acc += (cs[s] + BLK - 1) & ~(BLK - 1);
        }
        bp[S] = acc;
        for (int s = 0; s < S; s++) hdr[4 + s] = bp[s];      // cursors = basePad[s]
        for (int j = 0; j <= S; j++) hdr[8 + j] = bp[j];     // basePad
    }
    __syncthreads();
    for (int s = 0; s < S; s++) {
        for (int i = bp[s] + cs[s] + t; i < bp[s + 1]; i += blockDim.x) perm[i] = -1;
    }
}

__global__ void k3_scatter(const int* __restrict__ sp, int* __restrict__ hdr,
                           int* __restrict__ perm, int N) {
    __shared__ int cnt[S];
    __shared__ int base[S];
    int t = threadIdx.x;
    int n = blockIdx.x * BLK + t;
    if (t < S) cnt[t] = 0;
    int i64 = hdr[14];
    __syncthreads();
    int s = 0, r = 0;
    bool valid = (n < N);
    if (valid) {
        s = load_species(sp, i64, n);
        r = atomicAdd(&cnt[s], 1);
    }
    __syncthreads();
    if (t < S) base[t] = atomicAdd(&hdr[4 + t], cnt[t]);
    __syncthreads();
    if (valid) perm[base[s] + r] = n;
}

__device__ __forceinline__ u32 f2bf(float f) {
    u32 u = __float_as_uint(f);
    u32 r = ((u >> 16) & 1u) + 0x7fffu;
    return (u + r) >> 16;
}

__device__ __forceinline__ float silu(float v) {
    float e = __expf(-v);
    return v * __builtin_amdgcn_rcpf(1.0f + e);
}

__global__ __launch_bounds__(BLK, 2) void k4_mlp(
    const void* __restrict__ rf,              // [N][L][16] fp32 or bf16
    const void* __restrict__ W1,              // [L][S][16][32]
    const void* __restrict__ W2,              // [L][S][32][32]
    const void* __restrict__ W3,              // [L][S][32][32]
    const void* __restrict__ W4,              // [L][S][32][16]
    const int* __restrict__ hdr,
    const int* __restrict__ perm,
    void* __restrict__ outp)                  // [N][L][16], same dtype
{
    __shared__ float wlds[L * WPL];           // 48 KB

    int p0 = blockIdx.x * BLK;
    int b1 = hdr[9], b2 = hdr[10], b3 = hdr[11], b4 = hdr[12];
    int isf32 = hdr[13];
    if (p0 >= b4) return;
    int s = (p0 >= b3) ? 3 : ((p0 >= b2) ? 2 : ((p0 >= b1) ? 1 : 0));
    s = __builtin_amdgcn_readfirstlane(s);

    // stage this species' weights (all 4 l) into LDS as fp32
    for (int idx = threadIdx.x; idx < L * WPL; idx += BLK) {
        int l = idx / WPL;
        int r = idx - l * WPL;
        const void* base;
        size_t off;
        if (r < 512)        { base = W1; off = (size_t)(l * S + s) * 512  + r; }
        else if (r < 1536)  { base = W2; off = (size_t)(l * S + s) * 1024 + (r - 512); }
        else if (r < 2560)  { base = W3; off = (size_t)(l * S + s) * 1024 + (r - 1536); }
        else                { base = W4; off = (size_t)(l * S + s) * 512  + (r - 2560); }
        wlds[idx] = isf32 ? ((const float*)base)[off]
                          : __uint_as_float(((u32)((const unsigned short*)base)[off]) << 16);
    }
    __syncthreads();

    int n = perm[p0 + threadIdx.x];
    if (n < 0) return;  // padding slot

#pragma unroll 1
    for (int l = 0; l < L; l++) {
        const float* lw = &wlds[l * WPL];
        float x[NM];
        if (isf32) {
            const float4* xf = (const float4*)rf;
#pragma unroll
            for (int j = 0; j < 4; j++) {
                float4 q = xf[(size_t)n * 16 + l * 4 + j];
                x[4 * j] = q.x; x[4 * j + 1] = q.y; x[4 * j + 2] = q.z; x[4 * j + 3] = q.w;
            }
        } else {
            const uint4* xb = (const uint4*)rf;
#pragma unroll
            for (int j = 0; j < 2; j++) {
                uint4 q = xb[(size_t)n * 8 + l * 2 + j];
                u32 a0 = q.x, a1 = q.y, a2 = q.z, a3 = q.w;
                x[8 * j + 0] = __uint_as_float(a0 << 16);
                x[8 * j + 1] = __uint_as_float(a0 & 0xffff0000u);
                x[8 * j + 2] = __uint_as_float(a1 << 16);
                x[8 * j + 3] = __uint_as_float(a1 & 0xffff0000u);
                x[8 * j + 4] = __uint_as_float(a2 << 16);
                x[8 * j + 5] = __uint_as_float(a2 & 0xffff0000u);
                x[8 * j + 6] = __uint_as_float(a3 << 16);
                x[8 * j + 7] = __uint_as_float(a3 & 0xffff0000u);
            }
        }

        // layer 1: 16 -> 32
        float h[HID];
#pragma unroll
        for (int o = 0; o < HID; o++) h[o] = 0.0f;
#pragma unroll
        for (int i = 0; i < NM; i++) {
            float xv = x[i];
#pragma unroll
            for (int o = 0; o < HID; o++) h[o] += xv * lw[i * HID + o];
        }
#pragma unroll
        for (int o = 0; o < HID; o++) h[o] = silu(h[o]);

        // layer 2: 32 -> 32
        const float* w2 = lw + 512;
        float g[HID];
#pragma unroll
        for (int o = 0; o < HID; o++) g[o] = 0.0f;
#pragma unroll
        for (int i = 0; i < HID; i++) {
            float hv = h[i];
#pragma unroll
            for (int o = 0; o < HID; o++) g[o] += hv * w2[i * HID + o];
        }
#pragma unroll
        for (int o = 0; o < HID; o++) g[o] = silu(g[o]);

        // layer 3: 32 -> 32
        const float* w3 = lw + 1536;
#pragma unroll
        for (int o = 0; o < HID; o++) h[o] = 0.0f;
#pragma unroll
        for (int i = 0; i < HID; i++) {
            float gv = g[i];
#pragma unroll
            for (int o = 0; o < HID; o++) h[o] += gv * w3[i * HID + o];
        }
#pragma unroll
        for (int o = 0; o < HID; o++) h[o] = silu(h[o]);

        // layer 4: 32 -> 16
        const float* w4 = lw + 2560;
        float y[NM];
#pragma unroll
        for (int o = 0; o < NM; o++) y[o] = 0.0f;
#pragma unroll
        for (int i = 0; i < HID; i++) {
            float hv = h[i];
#pragma unroll
            for (int o = 0; o < NM; o++) y[o] += hv * w4[i * NM + o];
        }

        if (isf32) {
            float4* of = (float4*)outp;
#pragma unroll
            for (int j = 0; j < 4; j++)
                of[(size_t)n * 16 + l * 4 + j] =
                    make_float4(y[4 * j], y[4 * j + 1], y[4 * j + 2], y[4 * j + 3]);
        } else {
            uint4* ob = (uint4*)outp;
            u32 ou[8];
#pragma unroll
            for (int ii = 0; ii < 8; ii++)
                ou[ii] = f2bf(y[2 * ii]) | (f2bf(y[2 * ii + 1]) << 16);
            ob[(size_t)n * 8 + l * 2]     = make_uint4(ou[0], ou[1], ou[2], ou[3]);
            ob[(size_t)n * 8 + l * 2 + 1] = make_uint4(ou[4], ou[5], ou[6], ou[7]);
        }
    }
}

extern "C" void kernel_launch(void* const* d_in, const int* in_sizes, int n_in,
                              void* d_out, int out_size, void* d_ws, size_t ws_size,
                              hipStream_t stream) {
    const void* rf     = d_in[0];
    const int* species = (const int*)d_in[1];
    const void* W1     = d_in[2];
    const void* W2     = d_in[3];
    const void* W3     = d_in[4];
    const void* W4     = d_in[5];

    int N = in_sizes[1];
    int* hdr  = (int*)d_ws;
    int* perm = hdr + 16;

    int nb    = (N + BLK - 1) / BLK;
    int grid4 = (N + S * (BLK - 1) + BLK - 1) / BLK;  // covers max padded total

    k0_init<<<dim3(1), dim3(64), 0, stream>>>(hdr);
    k_detect<<<dim3(1), dim3(64), 0, stream>>>((const u32*)rf, (const u32*)species, hdr);
    k1_hist<<<dim3(nb), dim3(BLK), 0, stream>>>(species, hdr, N);
    k2_scan<<<dim3(1), dim3(BLK), 0, stream>>>(hdr, perm);
    k3_scatter<<<dim3(nb), dim3(BLK), 0, stream>>>(species, hdr, perm, N);
    k4_mlp<<<dim3(grid4), dim3(BLK), 0, stream>>>(rf, W1, W2, W3, W4, hdr, perm, d_out);
}

// Round 3
// 492.295 us; speedup vs baseline: 1.2552x; 1.2552x over previous
//
#include <hip/hip_runtime.h>
#include <stdint.h>

typedef unsigned int u32;
typedef unsigned long long u64;

constexpr int L   = 4;
constexpr int S   = 4;
constexpr int NM  = 16;
constexpr int HID = 32;
constexpr int BLK = 256;
constexpr int NFRAG = 7;                       // A-frags per (l,s): L1:1, L2:2, L3:2, L4:2
constexpr int WF_ENTRIES = L * S * NFRAG * 64; // 7168 uint4 entries
constexpr int WS_PERM_INT = (256 + WF_ENTRIES * 16) / 4;  // perm after hdr+wfrag

typedef short  s16x8  __attribute__((ext_vector_type(8)));
typedef float  f32x16 __attribute__((ext_vector_type(16)));

// ws: [0,64B) hdr ints: [0..3] counts, [4..7] cursors, [8..12] basePad,
//     [13] fp32 flag, [14] int64 flag. wfrag uint4 at byte 256. perm at int WS_PERM_INT.

__global__ void k0_init(int* hdr) {
    if (threadIdx.x < 16) hdr[threadIdx.x] = 0;
}

__global__ void k_detect(const u32* __restrict__ rfw, const u32* __restrict__ spw,
                         int* __restrict__ hdr) {
    int t = threadIdx.x;  // one wave
    u32 w  = rfw[t];
    u32 lo = w & 0xffffu;
    u32 e  = (lo >> 7) & 0xffu;
    int plausible = (lo == 0u || (e >= 90u && e <= 141u)) ? 1 : 0;
    u64 pm = __ballot(plausible);
    u64 om = __ballot(spw[2 * t + 1] != 0u);
    if (t == 0) {
        hdr[13] = (__popcll(pm) < 48) ? 1 : 0;  // floats are fp32
        hdr[14] = (om == 0ull) ? 1 : 0;         // species is int64
    }
}

__device__ __forceinline__ int load_species(const int* sp, int i64, int n) {
    return i64 ? sp[2 * n] : sp[n];
}

__global__ void k1_hist(const int* __restrict__ sp, int* __restrict__ hdr, int N) {
    __shared__ int cnt[S];
    int t = threadIdx.x;
    int n = blockIdx.x * BLK + t;
    if (t < S) cnt[t] = 0;
    int i64 = hdr[14];
    __syncthreads();
    if (n < N) atomicAdd(&cnt[load_species(sp, i64, n)], 1);
    __syncthreads();
    if (t < S) atomicAdd(&hdr[t], cnt[t]);
}

__global__ void k2_scan(int* __restrict__ hdr, int* __restrict__ perm) {
    __shared__ int bp[S + 1];
    __shared__ int cs[S];
    int t = threadIdx.x;
    if (t == 0) {
        int acc = 0;
        for (int s = 0; s < S; s++) {
            bp[s] = acc;
            cs[s] = hdr[s];
            acc += (cs[s] + BLK - 1) & ~(BLK - 1);
        }
        bp[S] = acc;
        for (int s = 0; s < S; s++) hdr[4 + s] = bp[s];
        for (int j = 0; j <= S; j++) hdr[8 + j] = bp[j];
    }
    __syncthreads();
    for (int s = 0; s < S; s++) {
        for (int i = bp[s] + cs[s] + t; i < bp[s + 1]; i += blockDim.x) perm[i] = -1;
    }
}

__global__ void k3_scatter(const int* __restrict__ sp, int* __restrict__ hdr,
                           int* __restrict__ perm, int N) {
    __shared__ int cnt[S];
    __shared__ int base[S];
    int t = threadIdx.x;
    int n = blockIdx.x * BLK + t;
    if (t < S) cnt[t] = 0;
    int i64 = hdr[14];
    __syncthreads();
    int s = 0, r = 0;
    bool valid = (n < N);
    if (valid) {
        s = load_species(sp, i64, n);
        r = atomicAdd(&cnt[s], 1);
    }
    __syncthreads();
    if (t < S) base[t] = atomicAdd(&hdr[4 + t], cnt[t]);
    __syncthreads();
    if (valid) perm[base[s] + r] = n;
}

// Pre-swizzle weights into 32x32x16 A-fragment order (transposed: A[m=out][k=in]).
// Entry e = ((l*S+s)*NFRAG + f)*64 + lane. Lane holds k = 8*(lane>>5)+j, m = lane&31.
__global__ void k_wprep(const void* __restrict__ W1, const void* __restrict__ W2,
                        const void* __restrict__ W3, const void* __restrict__ W4,
                        const int* __restrict__ hdr, uint4* __restrict__ wf) {
    int e = blockIdx.x * BLK + threadIdx.x;
    if (e >= WF_ENTRIES) return;
    int lam = e & 63;
    int f   = (e >> 6) % NFRAG;
    int ls  = e / (64 * NFRAG);
    int m = lam & 31, h = lam >> 5;
    int isf32 = hdr[13];
    unsigned short vals[8];
#pragma unroll
    for (int j = 0; j < 8; j++) {
        int k = 8 * h + j;
        const void* base; size_t off; bool zero = false;
        if (f == 0)      { base = W1; off = (size_t)ls * 512  + (size_t)k * 32 + m; }
        else if (f <= 2) { base = W2; off = (size_t)ls * 1024 + (size_t)(k + 16 * (f - 1)) * 32 + m; }
        else if (f <= 4) { base = W3; off = (size_t)ls * 1024 + (size_t)(k + 16 * (f - 3)) * 32 + m; }
        else             { zero = (m >= NM); base = W4;
                           off = (size_t)ls * 512 + (size_t)(k + 16 * (f - 5)) * NM + (m & 15); }
        unsigned short v;
        if (zero) v = 0;
        else if (isf32) {
            u32 u = __float_as_uint(((const float*)base)[off]);
            u32 r = ((u >> 16) & 1u) + 0x7fffu;
            v = (unsigned short)((u + r) >> 16);
        } else v = ((const unsigned short*)base)[off];
        vals[j] = v;
    }
    uint4 q;
    q.x = vals[0] | ((u32)vals[1] << 16);
    q.y = vals[2] | ((u32)vals[3] << 16);
    q.z = vals[4] | ((u32)vals[5] << 16);
    q.w = vals[6] | ((u32)vals[7] << 16);
    wf[e] = q;
}

__device__ __forceinline__ u32 pack_bf16_hu(float a, float b) {
    u32 ua = __float_as_uint(a) + 0x8000u;   // round half-up
    u32 ub = __float_as_uint(b) + 0x8000u;
    return (ua >> 16) | (ub & 0xffff0000u);
}

__device__ __forceinline__ float silu(float v) {
    float e = __expf(-v);
    return v * __builtin_amdgcn_rcpf(1.0f + e);
}

// D (C/D layout) -> next-layer B frags (Ba: k=0..15, Bb: k=16..31), with SiLU.
__device__ __forceinline__ void d_to_b(const f32x16& d, int h, s16x8& Ba, s16x8& Bb) {
    u32 P[8];
#pragma unroll
    for (int i = 0; i < 8; i++)
        P[i] = pack_bf16_hu(silu(d[2 * i]), silu(d[2 * i + 1]));
    u32 E[8];
#pragma unroll
    for (int i = 0; i < 8; i++) E[i] = (u32)__shfl_xor((int)P[i], 32, 64);
    u32 q[8];
#pragma unroll
    for (int b = 0; b < 2; b++) {
        int idx = 2 * h + 4 * b;
        q[4 * b + 0] = h ? E[idx]     : P[idx];
        q[4 * b + 1] = h ? E[idx + 1] : P[idx + 1];
        q[4 * b + 2] = h ? P[idx]     : E[idx];
        q[4 * b + 3] = h ? P[idx + 1] : E[idx + 1];
    }
    Ba = __builtin_bit_cast(s16x8, make_uint4(q[0], q[1], q[2], q[3]));
    Bb = __builtin_bit_cast(s16x8, make_uint4(q[4], q[5], q[6], q[7]));
}

__global__ __launch_bounds__(BLK, 4) void k4_mlp(
    const void* __restrict__ rf, const int* __restrict__ hdr,
    const int* __restrict__ perm, const uint4* __restrict__ wf,
    void* __restrict__ outp)
{
    __shared__ uint4 lw[L * NFRAG * 64];   // 28 KB, fragment order

    int p0 = blockIdx.x * BLK;
    int b1 = hdr[9], b2 = hdr[10], b3 = hdr[11], b4 = hdr[12];
    int isf32 = hdr[13];
    if (p0 >= b4) return;
    int s = (p0 >= b3) ? 3 : ((p0 >= b2) ? 2 : ((p0 >= b1) ? 1 : 0));
    s = __builtin_amdgcn_readfirstlane(s);

#pragma unroll
    for (int c = 0; c < 7; c++) {
        int idx = threadIdx.x + c * BLK;   // < 1792
        int l = idx / (NFRAG * 64);
        int r = idx - l * (NFRAG * 64);
        lw[idx] = wf[(size_t)((l * S + s) * NFRAG) * 64 + r];
    }
    __syncthreads();

    int wv   = threadIdx.x >> 6;
    int lane = threadIdx.x & 63;
    int col  = lane & 31;
    int h    = lane >> 5;

    int   n_t[2];
#pragma unroll
    for (int t = 0; t < 2; t++) n_t[t] = perm[p0 + wv * 64 + t * 32 + col];

    for (int l = 0; l < L; l++) {
        s16x8 fr[NFRAG];
#pragma unroll
        for (int f = 0; f < NFRAG; f++)
            fr[f] = __builtin_bit_cast(s16x8, lw[(l * NFRAG + f) * 64 + lane]);

#pragma unroll
        for (int t = 0; t < 2; t++) {
            int n = n_t[t];
            int nn = n < 0 ? 0 : n;

            // layer-1 B frag straight from global: x[nn][l*16 + 8h + j]
            s16x8 B1;
            if (!isf32) {
                const char* xb = (const char*)rf;
                B1 = __builtin_bit_cast(s16x8,
                     *(const uint4*)(xb + (size_t)nn * 128 + l * 32 + h * 16));
            } else {
                const float* xf = (const float*)rf + (size_t)nn * 64 + l * 16 + 8 * h;
                u32 q0 = pack_bf16_hu(xf[0], xf[1]);
                u32 q1 = pack_bf16_hu(xf[2], xf[3]);
                u32 q2 = pack_bf16_hu(xf[4], xf[5]);
                u32 q3 = pack_bf16_hu(xf[6], xf[7]);
                B1 = __builtin_bit_cast(s16x8, make_uint4(q0, q1, q2, q3));
            }

            f32x16 z = {0.0f};
            f32x16 d1 = __builtin_amdgcn_mfma_f32_32x32x16_bf16(fr[0], B1, z, 0, 0, 0);

            s16x8 Ba, Bb;
            d_to_b(d1, h, Ba, Bb);
            f32x16 d2 = __builtin_amdgcn_mfma_f32_32x32x16_bf16(fr[1], Ba, z, 0, 0, 0);
            d2 = __builtin_amdgcn_mfma_f32_32x32x16_bf16(fr[2], Bb, d2, 0, 0, 0);

            d_to_b(d2, h, Ba, Bb);
            f32x16 d3 = __builtin_amdgcn_mfma_f32_32x32x16_bf16(fr[3], Ba, z, 0, 0, 0);
            d3 = __builtin_amdgcn_mfma_f32_32x32x16_bf16(fr[4], Bb, d3, 0, 0, 0);

            d_to_b(d3, h, Ba, Bb);
            f32x16 d4 = __builtin_amdgcn_mfma_f32_32x32x16_bf16(fr[5], Ba, z, 0, 0, 0);
            d4 = __builtin_amdgcn_mfma_f32_32x32x16_bf16(fr[6], Bb, d4, 0, 0, 0);

            // epilogue: features 0..15 of pair n live in regs 0..7 of lanes n, n^32
            if (!isf32) {
                u32 P[4];
#pragma unroll
                for (int i = 0; i < 4; i++) P[i] = pack_bf16_hu(d4[2 * i], d4[2 * i + 1]);
                u32 E[4];
#pragma unroll
                for (int i = 0; i < 4; i++) E[i] = (u32)__shfl_xor((int)P[i], 32, 64);
                if (n >= 0) {
                    uint4 v = h ? make_uint4(E[2], E[3], P[2], P[3])
                                : make_uint4(P[0], P[1], E[0], E[1]);
                    char* ob = (char*)outp;
                    *(uint4*)(ob + (size_t)n * 128 + l * 32 + h * 16) = v;
                }
            } else {
                float E[8];
#pragma unroll
                for (int i = 0; i < 8; i++)
                    E[i] = __uint_as_float((u32)__shfl_xor((int)__float_as_uint(d4[i]), 32, 64));
                if (n >= 0) {
                    float* of = (float*)outp + (size_t)n * 64 + l * 16 + 8 * h;
                    if (h == 0) {
                        of[0] = d4[0]; of[1] = d4[1]; of[2] = d4[2]; of[3] = d4[3];
                        of[4] = E[0];  of[5] = E[1];  of[6] = E[2];  of[7] = E[3];
                    } else {
                        of[0] = E[4];  of[1] = E[5];  of[2] = E[6];  of[3] = E[7];
                        of[4] = d4[4]; of[5] = d4[5]; of[6] = d4[6]; of[7] = d4[7];
                    }
                }
            }
        }
    }
}

extern "C" void kernel_launch(void* const* d_in, const int* in_sizes, int n_in,
                              void* d_out, int out_size, void* d_ws, size_t ws_size,
                              hipStream_t stream) {
    const void* rf     = d_in[0];
    const int* species = (const int*)d_in[1];
    const void* W1     = d_in[2];
    const void* W2     = d_in[3];
    const void* W3     = d_in[4];
    const void* W4     = d_in[5];

    int N = in_sizes[1];
    int* hdr   = (int*)d_ws;
    uint4* wf  = (uint4*)((char*)d_ws + 256);
    int* perm  = (int*)d_ws + WS_PERM_INT;

    int nb    = (N + BLK - 1) / BLK;
    int nwp   = (WF_ENTRIES + BLK - 1) / BLK;
    int grid4 = (N + S * (BLK - 1) + BLK - 1) / BLK;

    k0_init  <<<dim3(1),    dim3(64),  0, stream>>>(hdr);
    k_detect <<<dim3(1),    dim3(64),  0, stream>>>((const u32*)rf, (const u32*)species, hdr);
    k_wprep  <<<dim3(nwp),  dim3(BLK), 0, stream>>>(W1, W2, W3, W4, hdr, wf);
    k1_hist  <<<dim3(nb),   dim3(BLK), 0, stream>>>(species, hdr, N);
    k2_scan  <<<dim3(1),    dim3(BLK), 0, stream>>>(hdr, perm);
    k3_scatter<<<dim3(nb),  dim3(BLK), 0, stream>>>(species, hdr, perm, N);
    k4_mlp   <<<dim3(grid4),dim3(BLK), 0, stream>>>(rf, hdr, perm, wf, d_out);
}